// Round 1
// baseline (3512.580 us; speedup 1.0000x reference)
//
#include <hip/hip_runtime.h>
#include <hip/hip_cooperative_groups.h>

namespace cg = cooperative_groups;

#define NB    32
#define SEQ   128
#define WCH   20
#define CED   50
#define NFLT  64
#define WDIM  300
#define HD    512
#define NWORD 4096
#define LPAD  11
#define NEGV  -10000.0f

typedef float f32x4 __attribute__((ext_vector_type(4)));
typedef __bf16 bf16x8 __attribute__((ext_vector_type(8)));
typedef unsigned short u16x8 __attribute__((ext_vector_type(8)));

static __device__ __forceinline__ unsigned short f2bf(float f) {
  unsigned u = __builtin_bit_cast(unsigned, f);
  u += 0x7fffu + ((u >> 16) & 1u);
  return (unsigned short)(u >> 16);
}
static __device__ __forceinline__ float bf2f(unsigned short s) {
  unsigned u = ((unsigned)s) << 16;
  return __builtin_bit_cast(float, u);
}
static __device__ __forceinline__ float sigf(float x) { return 1.0f / (1.0f + expf(-x)); }

// ---------------------------------------------------------------- char CNN
__global__ __launch_bounds__(256) void conv_kernel(
    const int* __restrict__ char_ids, const float* __restrict__ char_embed,
    const float* __restrict__ w2, const float* __restrict__ b2,
    const float* __restrict__ w3, const float* __restrict__ b3,
    const float* __restrict__ w4, const float* __restrict__ b4,
    const float* __restrict__ w5, const float* __restrict__ b5,
    float* __restrict__ ch)
{
  __shared__ __align__(16) float xT[CED][WCH];   // transposed: [c][p]
  int wi = blockIdx.x;
  int tid = threadIdx.x;
  for (int e = tid; e < WCH * CED; e += 256) {
    int p = e / CED, c = e - p * CED;
    int cid = char_ids[wi * WCH + p];
    xT[c][p] = char_embed[cid * CED + c];
  }
  __syncthreads();
  int w = tid >> 6, f = tid & 63;      // wave w <-> kernel size k=w+2, lane=filter
  int k = w + 2;
  int P = WCH - k + 1;
  const float* cw = (w == 0) ? w2 : (w == 1) ? w3 : (w == 2) ? w4 : w5;
  const float* cb = (w == 0) ? b2 : (w == 1) ? b3 : (w == 2) ? b4 : b5;
  float acc[19];
  #pragma unroll
  for (int p = 0; p < 19; p++) acc[p] = 0.f;
  for (int c = 0; c < CED; c++) {
    float xr[20];
    const float4* rowp = (const float4*)&xT[c][0];
    #pragma unroll
    for (int q = 0; q < 5; q++) {
      float4 v = rowp[q];
      xr[4*q+0] = v.x; xr[4*q+1] = v.y; xr[4*q+2] = v.z; xr[4*q+3] = v.w;
    }
    #pragma unroll
    for (int dw = 0; dw < 5; dw++) {
      if (dw < k) {
        float wv = cw[(dw * CED + c) * NFLT + f];
        #pragma unroll
        for (int p = 0; p < 19; p++) {
          if (p < P) acc[p] += xr[p + dw] * wv;
        }
      }
    }
  }
  float m = acc[0];
  #pragma unroll
  for (int p = 1; p < 19; p++) if (p < P) m = fmaxf(m, acc[p]);
  // relu(max) == max(relu) ; bias uniform over positions
  ch[wi * 256 + w * 64 + f] = fmaxf(0.f, m + cb[f]);
}

// ---------------------------------------------------------------- word gather
__global__ void gather_word_kernel(const int* __restrict__ token_ids,
                                   const float* __restrict__ word_embed,
                                   float* __restrict__ word_in)
{
  int idx = blockIdx.x * 256 + threadIdx.x;
  if (idx < NWORD * WDIM) {
    int i = idx / WDIM, c = idx - i * WDIM;
    word_in[idx] = word_embed[token_ids[i] * WDIM + c];
  }
}

// ---------------------------------------------------------------- generic MFMA GEMM: C = act(A @ B^T + Cin + bias)
// A: (M,K) f32 row-major.  Bw: (N,K) f32 row-major.  128x128 tile, BK=32, 4 waves.
__global__ __launch_bounds__(256) void gemm_bt_kernel(
    const float* __restrict__ A, const float* __restrict__ Bw,
    const float* __restrict__ bias, const float* __restrict__ Cin,
    float* __restrict__ Cout, unsigned short* __restrict__ Cbf,
    int M, int N, int K, int act, int gridN)
{
  __shared__ __align__(16) unsigned short As[128 * 32];
  __shared__ __align__(16) unsigned short Bs[128 * 32];
  int bid = blockIdx.x;
  int tm = bid / gridN, tn = bid - tm * gridN;
  int m0 = tm * 128, n0 = tn * 128;
  int tid = threadIdx.x;
  int lane = tid & 63, w = tid >> 6;
  int wr = (w >> 1) * 64, wc = (w & 1) * 64;
  f32x4 acc[4][4] = {};
  int fr = lane & 15, fk = (lane >> 4) * 8;

  for (int k0 = 0; k0 < K; k0 += 32) {
    __syncthreads();
    #pragma unroll
    for (int i = 0; i < 16; i++) {
      int e = tid + i * 256;          // 0..4095
      int r = e >> 5, c = e & 31;
      int kx = k0 + c;
      int ra = m0 + r, rb = n0 + r;
      float av = (kx < K && ra < M) ? A[(size_t)ra * K + kx] : 0.f;
      float bv = (kx < K && rb < N) ? Bw[(size_t)rb * K + kx] : 0.f;
      As[r * 32 + c] = f2bf(av);
      Bs[r * 32 + c] = f2bf(bv);
    }
    __syncthreads();
    bf16x8 a[4], b[4];
    #pragma unroll
    for (int mt = 0; mt < 4; mt++)
      a[mt] = *(const bf16x8*)&As[(wr + mt * 16 + fr) * 32 + fk];
    #pragma unroll
    for (int nt = 0; nt < 4; nt++)
      b[nt] = *(const bf16x8*)&Bs[(wc + nt * 16 + fr) * 32 + fk];
    #pragma unroll
    for (int mt = 0; mt < 4; mt++)
      #pragma unroll
      for (int nt = 0; nt < 4; nt++)
        acc[mt][nt] = __builtin_amdgcn_mfma_f32_16x16x32_bf16(a[mt], b[nt], acc[mt][nt], 0, 0, 0);
  }

  #pragma unroll
  for (int mt = 0; mt < 4; mt++) {
    #pragma unroll
    for (int nt = 0; nt < 4; nt++) {
      #pragma unroll
      for (int j = 0; j < 4; j++) {
        int row = m0 + wr + mt * 16 + (lane >> 4) * 4 + j;
        int col = n0 + wc + nt * 16 + (lane & 15);
        if (row < M && col < N) {
          float v = acc[mt][nt][j];
          if (Cin)  v += Cin[(size_t)row * N + col];
          if (bias) v += bias[col];
          if (act == 1)      v = tanhf(v);
          else if (act == 2) v = sigf(v);
          if (Cbf) Cbf[(size_t)row * N + col] = f2bf(v);
          else     Cout[(size_t)row * N + col] = v;
        }
      }
    }
  }
}

// ---------------------------------------------------------------- gate combine
__global__ void feats_kernel(const float* __restrict__ g, const float* __restrict__ word_in,
                             const float* __restrict__ char_in, float* __restrict__ feats)
{
  int idx = blockIdx.x * 256 + threadIdx.x;
  if (idx < NWORD * WDIM) {
    float gg = g[idx];
    feats[idx] = gg * word_in[idx] + (1.f - gg) * char_in[idx];
  }
}

// ---------------------------------------------------------------- bidirectional LSTM (cooperative persistent)
// 64 blocks: dir = bid>>5, hidden-slice = bid&31 (16 units). whh slice lives in VGPR MFMA fragments.
__global__ __launch_bounds__(256) void lstm_kernel(
    const unsigned short* __restrict__ xg_f, const unsigned short* __restrict__ xg_b,
    const float* __restrict__ whh_f, const float* __restrict__ whh_b,
    const int* __restrict__ lens,
    float* __restrict__ lstm_out, unsigned short* __restrict__ h_glob)
{
  cg::grid_group grid = cg::this_grid();
  int bid = blockIdx.x;
  int dir = bid >> 5, sl = bid & 31;
  int hs0 = sl << 4;
  int tid = threadIdx.x, lane = tid & 63, w = tid >> 6;   // wave w = gate type (i,f,g,o)
  const unsigned short* xg = dir ? xg_b : xg_f;
  const float* whh = dir ? whh_b : whh_f;
  unsigned short* hg = h_glob + dir * (2 * NB * HD);

  // B-fragments of whh rows [w*512 + hs0 .. +16): col(lane&15)=hidden unit, k = kk*32+(lane>>4)*8+j
  bf16x8 wf[16];
  {
    const float* src = whh + (size_t)(w * HD + hs0 + (lane & 15)) * HD;
    #pragma unroll
    for (int kk = 0; kk < 16; kk++) {
      int kb = kk * 32 + (lane >> 4) * 8;
      u16x8 t;
      #pragma unroll
      for (int j2 = 0; j2 < 8; j2++) t[j2] = f2bf(src[kb + j2]);
      wf[kk] = __builtin_bit_cast(bf16x8, t);
    }
  }

  __shared__ float Gs[NB][68];          // [batch][gate*16 + hidden], padded stride
  int ub = tid >> 3, jp = tid & 7;      // update mapping: (batch, hidden pair)
  int mylen = lens[ub];
  float c0 = 0.f, c1 = 0.f;

  for (int s = 0; s < SEQ; s++) {
    int t = dir ? (SEQ - 1 - s) : s;
    const unsigned short* hsrc = hg + (s & 1) * (NB * HD);
    unsigned short* hdst = hg + ((s & 1) ^ 1) * (NB * HD);

    f32x4 acc0 = {0.f, 0.f, 0.f, 0.f};
    f32x4 acc1 = {0.f, 0.f, 0.f, 0.f};
    if (s > 0) {
      #pragma unroll
      for (int kk = 0; kk < 16; kk++) {
        int kb = kk * 32 + (lane >> 4) * 8;
        bf16x8 a0 = __builtin_bit_cast(bf16x8, *(const u16x8*)&hsrc[(lane & 15) * HD + kb]);
        bf16x8 a1 = __builtin_bit_cast(bf16x8, *(const u16x8*)&hsrc[(16 + (lane & 15)) * HD + kb]);
        acc0 = __builtin_amdgcn_mfma_f32_16x16x32_bf16(a0, wf[kk], acc0, 0, 0, 0);
        acc1 = __builtin_amdgcn_mfma_f32_16x16x32_bf16(a1, wf[kk], acc1, 0, 0, 0);
      }
    }
    #pragma unroll
    for (int j2 = 0; j2 < 4; j2++) {
      int bb = (lane >> 4) * 4 + j2;
      Gs[bb][w * 16 + (lane & 15)] = acc0[j2];
      Gs[16 + bb][w * 16 + (lane & 15)] = acc1[j2];
    }
    __syncthreads();

    int j0 = 2 * jp, j1 = j0 + 1;
    size_t xbase = ((size_t)(ub * SEQ + t)) * 2048 + hs0 + j0;
    float xi0 = bf2f(xg[xbase + 0]),    xi1 = bf2f(xg[xbase + 1]);
    float xf0 = bf2f(xg[xbase + 512]),  xf1 = bf2f(xg[xbase + 513]);
    float xG0 = bf2f(xg[xbase + 1024]), xG1 = bf2f(xg[xbase + 1025]);
    float xo0 = bf2f(xg[xbase + 1536]), xo1 = bf2f(xg[xbase + 1537]);

    float i0 = sigf(xi0 + Gs[ub][j0]),      i1 = sigf(xi1 + Gs[ub][j1]);
    float f0 = sigf(xf0 + Gs[ub][16 + j0]), f1 = sigf(xf1 + Gs[ub][16 + j1]);
    float g0 = tanhf(xG0 + Gs[ub][32 + j0]), g1 = tanhf(xG1 + Gs[ub][32 + j1]);
    float o0 = sigf(xo0 + Gs[ub][48 + j0]), o1 = sigf(xo1 + Gs[ub][48 + j1]);
    float cn0 = f0 * c0 + i0 * g0;
    float cn1 = f1 * c1 + i1 * g1;
    float hn0 = o0 * tanhf(cn0);
    float hn1 = o1 * tanhf(cn1);

    bool mk = (t < mylen);
    float hold0 = (s == 0) ? 0.f : bf2f(hsrc[ub * HD + hs0 + j0]);
    float hold1 = (s == 0) ? 0.f : bf2f(hsrc[ub * HD + hs0 + j1]);
    if (mk) { c0 = cn0; c1 = cn1; }
    float hk0 = mk ? hn0 : hold0, hk1 = mk ? hn1 : hold1;

    size_t obase = ((size_t)(ub * SEQ + t)) * 1024 + dir * HD + hs0 + j0;
    *(float2*)&lstm_out[obase] = make_float2(mk ? hn0 : 0.f, mk ? hn1 : 0.f);
    hdst[ub * HD + hs0 + j0] = f2bf(hk0);
    hdst[ub * HD + hs0 + j1] = f2bf(hk1);

    __threadfence();
    grid.sync();
  }
}

// ---------------------------------------------------------------- output projection + NEG pads
__global__ __launch_bounds__(64) void logits_kernel(
    const float* __restrict__ lstm_out, const float* __restrict__ out_w,
    const float* __restrict__ out_b, float* __restrict__ lg)
{
  int rw = blockIdx.x, j = threadIdx.x;
  const float* row = lstm_out + (size_t)rw * 1024;
  float s[9];
  #pragma unroll
  for (int l = 0; l < 9; l++) s[l] = 0.f;
  for (int e = j; e < 1024; e += 64) {
    float x = row[e];
    #pragma unroll
    for (int l = 0; l < 9; l++) s[l] += x * out_w[l * 1024 + e];
  }
  #pragma unroll
  for (int l = 0; l < 9; l++) {
    #pragma unroll
    for (int off = 32; off > 0; off >>= 1) s[l] += __shfl_xor(s[l], off);
  }
  float v = NEGV;
  if (j < 9) {
    float r = (j==0)?s[0]:(j==1)?s[1]:(j==2)?s[2]:(j==3)?s[3]:(j==4)?s[4]:
              (j==5)?s[5]:(j==6)?s[6]:(j==7)?s[7]:s[8];
    v = r + out_b[j];
  }
  if (j < LPAD) lg[(size_t)rw * LPAD + j] = v;
}

// ---------------------------------------------------------------- CRF gold score
__global__ __launch_bounds__(64) void crf_gold_kernel(
    const float* __restrict__ lg, const int* __restrict__ labels,
    const int* __restrict__ lens, const float* __restrict__ trn, float* __restrict__ gold)
{
  int b = blockIdx.x, j = threadIdx.x;
  int len = lens[b];
  const int* lab = labels + b * SEQ;
  const float* l0 = lg + (size_t)b * SEQ * LPAD;
  float s = 0.f;
  for (int t = j; t < SEQ; t += 64) {
    if (t < len) {
      s += l0[t * LPAD + lab[t]];
      if (t >= 1) s += trn[lab[t] * LPAD + lab[t - 1]];
    }
  }
  #pragma unroll
  for (int off = 32; off > 0; off >>= 1) s += __shfl_xor(s, off);
  if (j == 0) {
    s += trn[lab[0] * LPAD + 9];          // trn[lab0, START]
    s += trn[10 * LPAD + lab[len - 1]];   // trn[END, last]
    gold[b] = s;
  }
}

// ---------------------------------------------------------------- CRF norm + final loglik
__global__ __launch_bounds__(64) void crf_norm_kernel(
    const float* __restrict__ lg, const int* __restrict__ lens,
    const float* __restrict__ trn, const float* __restrict__ gold, float* __restrict__ out_ll)
{
  int b = blockIdx.x, i = threadIdx.x;
  int len = lens[b];
  const float* l0 = lg + (size_t)b * SEQ * LPAD;
  bool act = (i < LPAD);
  float trow[LPAD];
  #pragma unroll
  for (int jj = 0; jj < LPAD; jj++) trow[jj] = act ? trn[i * LPAD + jj] : 0.f;
  float alpha = act ? (l0[i] + trow[9]) : -1e30f;

  for (int t = 1; t < SEQ; t++) {
    float vj[LPAD];
    #pragma unroll
    for (int jj = 0; jj < LPAD; jj++) vj[jj] = __shfl(alpha, jj) + trow[jj];
    float mx = vj[0];
    #pragma unroll
    for (int jj = 1; jj < LPAD; jj++) mx = fmaxf(mx, vj[jj]);
    float sum = 0.f;
    #pragma unroll
    for (int jj = 0; jj < LPAD; jj++) sum += expf(vj[jj] - mx);
    float lgv = act ? l0[t * LPAD + i] : 0.f;
    float nw = mx + logf(sum) + lgv;
    if (act && t < len) alpha = nw;
  }
  float vj[LPAD];
  #pragma unroll
  for (int jj = 0; jj < LPAD; jj++) vj[jj] = __shfl(alpha, jj) + trn[10 * LPAD + jj];
  float mx = vj[0];
  #pragma unroll
  for (int jj = 1; jj < LPAD; jj++) mx = fmaxf(mx, vj[jj]);
  float sum = 0.f;
  #pragma unroll
  for (int jj = 0; jj < LPAD; jj++) sum += expf(vj[jj] - mx);
  if (i == 0) out_ll[b] = gold[b] - (mx + logf(sum));
}

// ================================================================ launch
extern "C" void kernel_launch(void* const* d_in, const int* in_sizes, int n_in,
                              void* d_out, int out_size, void* d_ws, size_t ws_size,
                              hipStream_t stream)
{
  (void)in_sizes; (void)n_in; (void)out_size; (void)ws_size;
  const int*   token_ids = (const int*)d_in[0];
  const int*   char_ids  = (const int*)d_in[1];
  const int*   lens      = (const int*)d_in[2];
  const int*   labels    = (const int*)d_in[3];
  const float* word_embed= (const float*)d_in[4];
  const float* char_embed= (const float*)d_in[5];
  const float* w2 = (const float*)d_in[6];  const float* cb2 = (const float*)d_in[7];
  const float* w3 = (const float*)d_in[8];  const float* cb3 = (const float*)d_in[9];
  const float* w4 = (const float*)d_in[10]; const float* cb4 = (const float*)d_in[11];
  const float* w5 = (const float*)d_in[12]; const float* cb5 = (const float*)d_in[13];
  const float* ff_w = (const float*)d_in[14]; const float* ff_b = (const float*)d_in[15];
  const float* wgate_w = (const float*)d_in[16];
  const float* cgate_w = (const float*)d_in[17];
  const float* gate_w  = (const float*)d_in[18];
  const float* wih_f = (const float*)d_in[19]; const float* whh_f = (const float*)d_in[20];
  const float* b_f   = (const float*)d_in[21];
  const float* wih_b = (const float*)d_in[22]; const float* whh_b = (const float*)d_in[23];
  const float* b_b   = (const float*)d_in[24];
  const float* out_w = (const float*)d_in[25]; const float* out_b = (const float*)d_in[26];
  const float* trn   = (const float*)d_in[27];

  char* ws = (char*)d_ws;
  size_t off = 0;
  auto alloc = [&](size_t bytes) { void* p = ws + off; off += (bytes + 255) & ~(size_t)255; return p; };
  float* ch       = (float*)alloc((size_t)NWORD * 256 * 4);
  float* word_in  = (float*)alloc((size_t)NWORD * WDIM * 4);
  float* char_in  = (float*)alloc((size_t)NWORD * WDIM * 4);
  float* t1       = (float*)alloc((size_t)NWORD * WDIM * 4);
  float* gbuf     = (float*)alloc((size_t)NWORD * WDIM * 4);
  float* feats    = (float*)alloc((size_t)NWORD * WDIM * 4);
  unsigned short* xgf = (unsigned short*)alloc((size_t)NWORD * 2048 * 2);
  unsigned short* xgb = (unsigned short*)alloc((size_t)NWORD * 2048 * 2);
  float* lstm_o   = (float*)alloc((size_t)NWORD * 1024 * 4);
  unsigned short* hglob = (unsigned short*)alloc((size_t)2 * 2 * NB * HD * 2);
  float* gold     = (float*)alloc((size_t)NB * 4);

  float* outp   = (float*)d_out;
  float* loglik = outp;
  float* logits = outp + NB;

  conv_kernel<<<NWORD, 256, 0, stream>>>(char_ids, char_embed, w2, cb2, w3, cb3, w4, cb4, w5, cb5, ch);
  gather_word_kernel<<<(NWORD * WDIM + 255) / 256, 256, 0, stream>>>(token_ids, word_embed, word_in);
  // char_in = ch @ ff_w.T + ff_b
  gemm_bt_kernel<<<32 * 3, 256, 0, stream>>>(ch, ff_w, ff_b, nullptr, char_in, nullptr, NWORD, 300, 256, 0, 3);
  // t1 = word_in @ wgate_w.T
  gemm_bt_kernel<<<32 * 3, 256, 0, stream>>>(word_in, wgate_w, nullptr, nullptr, t1, nullptr, NWORD, 300, 300, 0, 3);
  // t1 = tanh(t1 + char_in @ cgate_w.T)
  gemm_bt_kernel<<<32 * 3, 256, 0, stream>>>(char_in, cgate_w, nullptr, t1, t1, nullptr, NWORD, 300, 300, 1, 3);
  // g = sigmoid(t1 @ gate_w.T)
  gemm_bt_kernel<<<32 * 3, 256, 0, stream>>>(t1, gate_w, nullptr, nullptr, gbuf, nullptr, NWORD, 300, 300, 2, 3);
  feats_kernel<<<(NWORD * WDIM + 255) / 256, 256, 0, stream>>>(gbuf, word_in, char_in, feats);
  // xg = feats @ wih.T + b   (bf16 out)
  gemm_bt_kernel<<<32 * 16, 256, 0, stream>>>(feats, wih_f, b_f, nullptr, nullptr, xgf, NWORD, 2048, 300, 0, 16);
  gemm_bt_kernel<<<32 * 16, 256, 0, stream>>>(feats, wih_b, b_b, nullptr, nullptr, xgb, NWORD, 2048, 300, 0, 16);
  {
    void* args[] = { (void*)&xgf, (void*)&xgb, (void*)&whh_f, (void*)&whh_b,
                     (void*)&lens, (void*)&lstm_o, (void*)&hglob };
    hipLaunchCooperativeKernel((void*)lstm_kernel, dim3(64), dim3(256), args, 0, stream);
  }
  logits_kernel<<<NWORD, 64, 0, stream>>>(lstm_o, out_w, out_b, logits);
  crf_gold_kernel<<<NB, 64, 0, stream>>>(logits, labels, lens, trn, gold);
  crf_norm_kernel<<<NB, 64, 0, stream>>>(logits, lens, trn, gold, loglik);
}

// Round 2
// 2042.322 us; speedup vs baseline: 1.7199x; 1.7199x over previous
//
#include <hip/hip_runtime.h>

#define NB    32
#define SEQ   128
#define WCH   20
#define CED   50
#define NFLT  64
#define WDIM  300
#define HD    512
#define NWORD 4096
#define LPAD  11
#define NEGV  -10000.0f
#define LSTM_BLOCKS 64

typedef float f32x4 __attribute__((ext_vector_type(4)));
typedef __bf16 bf16x8 __attribute__((ext_vector_type(8)));
typedef unsigned short u16x8 __attribute__((ext_vector_type(8)));

static __device__ __forceinline__ unsigned short f2bf(float f) {
  unsigned u = __builtin_bit_cast(unsigned, f);
  u += 0x7fffu + ((u >> 16) & 1u);
  return (unsigned short)(u >> 16);
}
static __device__ __forceinline__ float bf2f(unsigned short s) {
  unsigned u = ((unsigned)s) << 16;
  return __builtin_bit_cast(float, u);
}
static __device__ __forceinline__ float sigf(float x) { return 1.0f / (1.0f + expf(-x)); }
static __device__ __forceinline__ void ldpair(const unsigned short* p, float& a, float& b) {
  unsigned u = *(const unsigned*)p;
  a = bf2f((unsigned short)(u & 0xffffu));
  b = bf2f((unsigned short)(u >> 16));
}

// ---------------------------------------------------------------- char CNN
__global__ __launch_bounds__(256) void conv_kernel(
    const int* __restrict__ char_ids, const float* __restrict__ char_embed,
    const float* __restrict__ w2, const float* __restrict__ b2,
    const float* __restrict__ w3, const float* __restrict__ b3,
    const float* __restrict__ w4, const float* __restrict__ b4,
    const float* __restrict__ w5, const float* __restrict__ b5,
    float* __restrict__ ch)
{
  __shared__ __align__(16) float xT[CED][WCH];   // transposed: [c][p]
  int wi = blockIdx.x;
  int tid = threadIdx.x;
  for (int e = tid; e < WCH * CED; e += 256) {
    int p = e / CED, c = e - p * CED;
    int cid = char_ids[wi * WCH + p];
    xT[c][p] = char_embed[cid * CED + c];
  }
  __syncthreads();
  int w = tid >> 6, f = tid & 63;      // wave w <-> kernel size k=w+2, lane=filter
  int k = w + 2;
  int P = WCH - k + 1;
  const float* cw = (w == 0) ? w2 : (w == 1) ? w3 : (w == 2) ? w4 : w5;
  const float* cb = (w == 0) ? b2 : (w == 1) ? b3 : (w == 2) ? b4 : b5;
  float acc[19];
  #pragma unroll
  for (int p = 0; p < 19; p++) acc[p] = 0.f;
  for (int c = 0; c < CED; c++) {
    float xr[20];
    const float4* rowp = (const float4*)&xT[c][0];
    #pragma unroll
    for (int q = 0; q < 5; q++) {
      float4 v = rowp[q];
      xr[4*q+0] = v.x; xr[4*q+1] = v.y; xr[4*q+2] = v.z; xr[4*q+3] = v.w;
    }
    #pragma unroll
    for (int dw = 0; dw < 5; dw++) {
      if (dw < k) {
        float wv = cw[(dw * CED + c) * NFLT + f];
        #pragma unroll
        for (int p = 0; p < 19; p++) {
          if (p < P) acc[p] += xr[p + dw] * wv;
        }
      }
    }
  }
  float m = acc[0];
  #pragma unroll
  for (int p = 1; p < 19; p++) if (p < P) m = fmaxf(m, acc[p]);
  ch[wi * 256 + w * 64 + f] = fmaxf(0.f, m + cb[f]);
}

// ---------------------------------------------------------------- word gather
__global__ void gather_word_kernel(const int* __restrict__ token_ids,
                                   const float* __restrict__ word_embed,
                                   float* __restrict__ word_in)
{
  int idx = blockIdx.x * 256 + threadIdx.x;
  if (idx < NWORD * WDIM) {
    int i = idx / WDIM, c = idx - i * WDIM;
    word_in[idx] = word_embed[token_ids[i] * WDIM + c];
  }
}

// ---------------------------------------------------------------- generic MFMA GEMM: C = act(A @ B^T + Cin + bias)
__global__ __launch_bounds__(256) void gemm_bt_kernel(
    const float* __restrict__ A, const float* __restrict__ Bw,
    const float* __restrict__ bias, const float* __restrict__ Cin,
    float* __restrict__ Cout, unsigned short* __restrict__ Cbf,
    int M, int N, int K, int act, int gridN)
{
  __shared__ __align__(16) unsigned short As[128 * 32];
  __shared__ __align__(16) unsigned short Bs[128 * 32];
  int bid = blockIdx.x;
  int tm = bid / gridN, tn = bid - tm * gridN;
  int m0 = tm * 128, n0 = tn * 128;
  int tid = threadIdx.x;
  int lane = tid & 63, w = tid >> 6;
  int wr = (w >> 1) * 64, wc = (w & 1) * 64;
  f32x4 acc[4][4] = {};
  int fr = lane & 15, fk = (lane >> 4) * 8;

  for (int k0 = 0; k0 < K; k0 += 32) {
    __syncthreads();
    #pragma unroll
    for (int i = 0; i < 16; i++) {
      int e = tid + i * 256;
      int r = e >> 5, c = e & 31;
      int kx = k0 + c;
      int ra = m0 + r, rb = n0 + r;
      float av = (kx < K && ra < M) ? A[(size_t)ra * K + kx] : 0.f;
      float bv = (kx < K && rb < N) ? Bw[(size_t)rb * K + kx] : 0.f;
      As[r * 32 + c] = f2bf(av);
      Bs[r * 32 + c] = f2bf(bv);
    }
    __syncthreads();
    bf16x8 a[4], b[4];
    #pragma unroll
    for (int mt = 0; mt < 4; mt++)
      a[mt] = *(const bf16x8*)&As[(wr + mt * 16 + fr) * 32 + fk];
    #pragma unroll
    for (int nt = 0; nt < 4; nt++)
      b[nt] = *(const bf16x8*)&Bs[(wc + nt * 16 + fr) * 32 + fk];
    #pragma unroll
    for (int mt = 0; mt < 4; mt++)
      #pragma unroll
      for (int nt = 0; nt < 4; nt++)
        acc[mt][nt] = __builtin_amdgcn_mfma_f32_16x16x32_bf16(a[mt], b[nt], acc[mt][nt], 0, 0, 0);
  }

  #pragma unroll
  for (int mt = 0; mt < 4; mt++) {
    #pragma unroll
    for (int nt = 0; nt < 4; nt++) {
      #pragma unroll
      for (int j = 0; j < 4; j++) {
        int row = m0 + wr + mt * 16 + (lane >> 4) * 4 + j;
        int col = n0 + wc + nt * 16 + (lane & 15);
        if (row < M && col < N) {
          float v = acc[mt][nt][j];
          if (Cin)  v += Cin[(size_t)row * N + col];
          if (bias) v += bias[col];
          if (act == 1)      v = tanhf(v);
          else if (act == 2) v = sigf(v);
          if (Cbf) Cbf[(size_t)row * N + col] = f2bf(v);
          else     Cout[(size_t)row * N + col] = v;
        }
      }
    }
  }
}

// ---------------------------------------------------------------- gate combine (+ barrier reset)
__global__ void feats_kernel(const float* __restrict__ g, const float* __restrict__ word_in,
                             const float* __restrict__ char_in, float* __restrict__ feats,
                             unsigned* __restrict__ bar)
{
  if (blockIdx.x == 0 && threadIdx.x < 64) bar[threadIdx.x] = 0u;
  int idx = blockIdx.x * 256 + threadIdx.x;
  if (idx < NWORD * WDIM) {
    float gg = g[idx];
    feats[idx] = gg * word_in[idx] + (1.f - gg) * char_in[idx];
  }
}

// ---------------------------------------------------------------- custom grid barrier
static __device__ __forceinline__ void gbarrier(unsigned* cnt, int step) {
  __syncthreads();                       // all waves' h-stores drained to cache
  if (threadIdx.x == 0) {
    __threadfence();                     // release: writeback so other XCDs see h
    __hip_atomic_fetch_add(cnt, 1u, __ATOMIC_RELAXED, __HIP_MEMORY_SCOPE_AGENT);
    unsigned target = (unsigned)LSTM_BLOCKS * (unsigned)(step + 1);
    while (__hip_atomic_load(cnt, __ATOMIC_RELAXED, __HIP_MEMORY_SCOPE_AGENT) < target) {
      __builtin_amdgcn_s_sleep(1);
    }
    __threadfence();                     // acquire: invalidate stale cached h
  }
  __syncthreads();
}

// ---------------------------------------------------------------- bidirectional LSTM (persistent)
// 64 blocks: dir = bid>>5, hidden-slice = bid&31 (16 units). whh slice lives in VGPR MFMA fragments.
__global__ __launch_bounds__(256) void lstm_kernel(
    const unsigned short* __restrict__ xg_f, const unsigned short* __restrict__ xg_b,
    const float* __restrict__ whh_f, const float* __restrict__ whh_b,
    const int* __restrict__ lens,
    float* __restrict__ lstm_out, unsigned short* __restrict__ h_glob,
    unsigned* __restrict__ bar)
{
  int bid = blockIdx.x;
  int dir = bid >> 5, sl = bid & 31;
  int hs0 = sl << 4;
  int tid = threadIdx.x, lane = tid & 63, w = tid >> 6;   // wave w = gate type (i,f,g,o)
  const unsigned short* xg = dir ? xg_b : xg_f;
  const float* whh = dir ? whh_b : whh_f;
  unsigned short* hg = h_glob + dir * (2 * NB * HD);

  // B-fragments of whh rows [w*512 + hs0 .. +16): col(lane&15)=hidden unit, k = kk*32+(lane>>4)*8+j
  bf16x8 wf[16];
  {
    const float* src = whh + (size_t)(w * HD + hs0 + (lane & 15)) * HD;
    #pragma unroll
    for (int kk = 0; kk < 16; kk++) {
      int kb = kk * 32 + (lane >> 4) * 8;
      u16x8 t;
      #pragma unroll
      for (int j2 = 0; j2 < 8; j2++) t[j2] = f2bf(src[kb + j2]);
      wf[kk] = __builtin_bit_cast(bf16x8, t);
    }
  }

  __shared__ float Gs[NB][68];          // [batch][gate*16 + hidden], padded stride
  int ub = tid >> 3, jp = tid & 7;      // update mapping: (batch, hidden pair)
  int j0 = 2 * jp, j1 = j0 + 1;
  int mylen = lens[ub];
  float c0 = 0.f, c1 = 0.f;
  float hprev0 = 0.f, hprev1 = 0.f;     // this thread's own h (for masked hold)

  // preload xg for s=0
  float xi0, xi1, xf0, xf1, xG0, xG1, xo0, xo1;
  {
    int t0 = dir ? (SEQ - 1) : 0;
    size_t xb = ((size_t)(ub * SEQ + t0)) * 2048 + hs0 + j0;
    ldpair(&xg[xb + 0],    xi0, xi1);
    ldpair(&xg[xb + 512],  xf0, xf1);
    ldpair(&xg[xb + 1024], xG0, xG1);
    ldpair(&xg[xb + 1536], xo0, xo1);
  }

  for (int s = 0; s < SEQ; s++) {
    int t = dir ? (SEQ - 1 - s) : s;
    const unsigned short* hsrc = hg + (s & 1) * (NB * HD);
    unsigned short* hdst = hg + ((s & 1) ^ 1) * (NB * HD);

    f32x4 acc0 = {0.f, 0.f, 0.f, 0.f};
    f32x4 acc1 = {0.f, 0.f, 0.f, 0.f};
    if (s > 0) {
      #pragma unroll
      for (int kk = 0; kk < 16; kk++) {
        int kb = kk * 32 + (lane >> 4) * 8;
        bf16x8 a0 = __builtin_bit_cast(bf16x8, *(const u16x8*)&hsrc[(lane & 15) * HD + kb]);
        bf16x8 a1 = __builtin_bit_cast(bf16x8, *(const u16x8*)&hsrc[(16 + (lane & 15)) * HD + kb]);
        acc0 = __builtin_amdgcn_mfma_f32_16x16x32_bf16(a0, wf[kk], acc0, 0, 0, 0);
        acc1 = __builtin_amdgcn_mfma_f32_16x16x32_bf16(a1, wf[kk], acc1, 0, 0, 0);
      }
    }
    #pragma unroll
    for (int j2 = 0; j2 < 4; j2++) {
      int bb = (lane >> 4) * 4 + j2;
      Gs[bb][w * 16 + (lane & 15)] = acc0[j2];
      Gs[16 + bb][w * 16 + (lane & 15)] = acc1[j2];
    }
    __syncthreads();

    float i0 = sigf(xi0 + Gs[ub][j0]),       i1 = sigf(xi1 + Gs[ub][j1]);
    float f0 = sigf(xf0 + Gs[ub][16 + j0]),  f1 = sigf(xf1 + Gs[ub][16 + j1]);
    float g0 = tanhf(xG0 + Gs[ub][32 + j0]), g1 = tanhf(xG1 + Gs[ub][32 + j1]);
    float o0 = sigf(xo0 + Gs[ub][48 + j0]),  o1 = sigf(xo1 + Gs[ub][48 + j1]);
    float cn0 = f0 * c0 + i0 * g0;
    float cn1 = f1 * c1 + i1 * g1;
    float hn0 = o0 * tanhf(cn0);
    float hn1 = o1 * tanhf(cn1);

    bool mk = (t < mylen);
    if (mk) { c0 = cn0; c1 = cn1; }
    float hk0 = mk ? hn0 : hprev0, hk1 = mk ? hn1 : hprev1;
    hprev0 = hk0; hprev1 = hk1;

    size_t obase = ((size_t)(ub * SEQ + t)) * 1024 + dir * HD + hs0 + j0;
    *(float2*)&lstm_out[obase] = make_float2(mk ? hn0 : 0.f, mk ? hn1 : 0.f);
    hdst[ub * HD + hs0 + j0] = f2bf(hk0);
    hdst[ub * HD + hs0 + j1] = f2bf(hk1);

    if (s + 1 < SEQ) {
      // issue next-step xg loads; their latency hides under the barrier wait
      int tn = dir ? (SEQ - 2 - s) : (s + 1);
      size_t xb = ((size_t)(ub * SEQ + tn)) * 2048 + hs0 + j0;
      float nxi0, nxi1, nxf0, nxf1, nxG0, nxG1, nxo0, nxo1;
      ldpair(&xg[xb + 0],    nxi0, nxi1);
      ldpair(&xg[xb + 512],  nxf0, nxf1);
      ldpair(&xg[xb + 1024], nxG0, nxG1);
      ldpair(&xg[xb + 1536], nxo0, nxo1);
      gbarrier(bar, s);
      xi0 = nxi0; xi1 = nxi1; xf0 = nxf0; xf1 = nxf1;
      xG0 = nxG0; xG1 = nxG1; xo0 = nxo0; xo1 = nxo1;
    }
  }
}

// ---------------------------------------------------------------- output projection + NEG pads
__global__ __launch_bounds__(64) void logits_kernel(
    const float* __restrict__ lstm_out, const float* __restrict__ out_w,
    const float* __restrict__ out_b, float* __restrict__ lg)
{
  int rw = blockIdx.x, j = threadIdx.x;
  const float* row = lstm_out + (size_t)rw * 1024;
  float s[9];
  #pragma unroll
  for (int l = 0; l < 9; l++) s[l] = 0.f;
  for (int e = j; e < 1024; e += 64) {
    float x = row[e];
    #pragma unroll
    for (int l = 0; l < 9; l++) s[l] += x * out_w[l * 1024 + e];
  }
  #pragma unroll
  for (int l = 0; l < 9; l++) {
    #pragma unroll
    for (int off = 32; off > 0; off >>= 1) s[l] += __shfl_xor(s[l], off);
  }
  float v = NEGV;
  if (j < 9) {
    float r = (j==0)?s[0]:(j==1)?s[1]:(j==2)?s[2]:(j==3)?s[3]:(j==4)?s[4]:
              (j==5)?s[5]:(j==6)?s[6]:(j==7)?s[7]:s[8];
    v = r + out_b[j];
  }
  if (j < LPAD) lg[(size_t)rw * LPAD + j] = v;
}

// ---------------------------------------------------------------- CRF gold score
__global__ __launch_bounds__(64) void crf_gold_kernel(
    const float* __restrict__ lg, const int* __restrict__ labels,
    const int* __restrict__ lens, const float* __restrict__ trn, float* __restrict__ gold)
{
  int b = blockIdx.x, j = threadIdx.x;
  int len = lens[b];
  const int* lab = labels + b * SEQ;
  const float* l0 = lg + (size_t)b * SEQ * LPAD;
  float s = 0.f;
  for (int t = j; t < SEQ; t += 64) {
    if (t < len) {
      s += l0[t * LPAD + lab[t]];
      if (t >= 1) s += trn[lab[t] * LPAD + lab[t - 1]];
    }
  }
  #pragma unroll
  for (int off = 32; off > 0; off >>= 1) s += __shfl_xor(s, off);
  if (j == 0) {
    s += trn[lab[0] * LPAD + 9];
    s += trn[10 * LPAD + lab[len - 1]];
    gold[b] = s;
  }
}

// ---------------------------------------------------------------- CRF norm + final loglik
__global__ __launch_bounds__(64) void crf_norm_kernel(
    const float* __restrict__ lg, const int* __restrict__ lens,
    const float* __restrict__ trn, const float* __restrict__ gold, float* __restrict__ out_ll)
{
  int b = blockIdx.x, i = threadIdx.x;
  int len = lens[b];
  const float* l0 = lg + (size_t)b * SEQ * LPAD;
  bool act = (i < LPAD);
  float trow[LPAD];
  #pragma unroll
  for (int jj = 0; jj < LPAD; jj++) trow[jj] = act ? trn[i * LPAD + jj] : 0.f;
  float alpha = act ? (l0[i] + trow[9]) : -1e30f;

  for (int t = 1; t < SEQ; t++) {
    float vj[LPAD];
    #pragma unroll
    for (int jj = 0; jj < LPAD; jj++) vj[jj] = __shfl(alpha, jj) + trow[jj];
    float mx = vj[0];
    #pragma unroll
    for (int jj = 1; jj < LPAD; jj++) mx = fmaxf(mx, vj[jj]);
    float sum = 0.f;
    #pragma unroll
    for (int jj = 0; jj < LPAD; jj++) sum += expf(vj[jj] - mx);
    float lgv = act ? l0[t * LPAD + i] : 0.f;
    float nw = mx + logf(sum) + lgv;
    if (act && t < len) alpha = nw;
  }
  float vj[LPAD];
  #pragma unroll
  for (int jj = 0; jj < LPAD; jj++) vj[jj] = __shfl(alpha, jj) + trn[10 * LPAD + jj];
  float mx = vj[0];
  #pragma unroll
  for (int jj = 1; jj < LPAD; jj++) mx = fmaxf(mx, vj[jj]);
  float sum = 0.f;
  #pragma unroll
  for (int jj = 0; jj < LPAD; jj++) sum += expf(vj[jj] - mx);
  if (i == 0) out_ll[b] = gold[b] - (mx + logf(sum));
}

// ================================================================ launch
extern "C" void kernel_launch(void* const* d_in, const int* in_sizes, int n_in,
                              void* d_out, int out_size, void* d_ws, size_t ws_size,
                              hipStream_t stream)
{
  (void)in_sizes; (void)n_in; (void)out_size; (void)ws_size;
  const int*   token_ids = (const int*)d_in[0];
  const int*   char_ids  = (const int*)d_in[1];
  const int*   lens      = (const int*)d_in[2];
  const int*   labels    = (const int*)d_in[3];
  const float* word_embed= (const float*)d_in[4];
  const float* char_embed= (const float*)d_in[5];
  const float* w2 = (const float*)d_in[6];  const float* cb2 = (const float*)d_in[7];
  const float* w3 = (const float*)d_in[8];  const float* cb3 = (const float*)d_in[9];
  const float* w4 = (const float*)d_in[10]; const float* cb4 = (const float*)d_in[11];
  const float* w5 = (const float*)d_in[12]; const float* cb5 = (const float*)d_in[13];
  const float* ff_w = (const float*)d_in[14]; const float* ff_b = (const float*)d_in[15];
  const float* wgate_w = (const float*)d_in[16];
  const float* cgate_w = (const float*)d_in[17];
  const float* gate_w  = (const float*)d_in[18];
  const float* wih_f = (const float*)d_in[19]; const float* whh_f = (const float*)d_in[20];
  const float* b_f   = (const float*)d_in[21];
  const float* wih_b = (const float*)d_in[22]; const float* whh_b = (const float*)d_in[23];
  const float* b_b   = (const float*)d_in[24];
  const float* out_w = (const float*)d_in[25]; const float* out_b = (const float*)d_in[26];
  const float* trn   = (const float*)d_in[27];

  char* ws = (char*)d_ws;
  size_t off = 0;
  auto alloc = [&](size_t bytes) { void* p = ws + off; off += (bytes + 255) & ~(size_t)255; return p; };
  float* ch       = (float*)alloc((size_t)NWORD * 256 * 4);
  float* word_in  = (float*)alloc((size_t)NWORD * WDIM * 4);
  float* char_in  = (float*)alloc((size_t)NWORD * WDIM * 4);
  float* t1       = (float*)alloc((size_t)NWORD * WDIM * 4);
  float* gbuf     = (float*)alloc((size_t)NWORD * WDIM * 4);
  float* feats    = (float*)alloc((size_t)NWORD * WDIM * 4);
  unsigned short* xgf = (unsigned short*)alloc((size_t)NWORD * 2048 * 2);
  unsigned short* xgb = (unsigned short*)alloc((size_t)NWORD * 2048 * 2);
  float* lstm_o   = (float*)alloc((size_t)NWORD * 1024 * 4);
  unsigned short* hglob = (unsigned short*)alloc((size_t)2 * 2 * NB * HD * 2);
  float* gold     = (float*)alloc((size_t)NB * 4);
  unsigned* bar   = (unsigned*)alloc(256);

  float* outp   = (float*)d_out;
  float* loglik = outp;
  float* logits = outp + NB;

  conv_kernel<<<NWORD, 256, 0, stream>>>(char_ids, char_embed, w2, cb2, w3, cb3, w4, cb4, w5, cb5, ch);
  gather_word_kernel<<<(NWORD * WDIM + 255) / 256, 256, 0, stream>>>(token_ids, word_embed, word_in);
  gemm_bt_kernel<<<32 * 3, 256, 0, stream>>>(ch, ff_w, ff_b, nullptr, char_in, nullptr, NWORD, 300, 256, 0, 3);
  gemm_bt_kernel<<<32 * 3, 256, 0, stream>>>(word_in, wgate_w, nullptr, nullptr, t1, nullptr, NWORD, 300, 300, 0, 3);
  gemm_bt_kernel<<<32 * 3, 256, 0, stream>>>(char_in, cgate_w, nullptr, t1, t1, nullptr, NWORD, 300, 300, 1, 3);
  gemm_bt_kernel<<<32 * 3, 256, 0, stream>>>(t1, gate_w, nullptr, nullptr, gbuf, nullptr, NWORD, 300, 300, 2, 3);
  feats_kernel<<<(NWORD * WDIM + 255) / 256, 256, 0, stream>>>(gbuf, word_in, char_in, feats, bar);
  gemm_bt_kernel<<<32 * 16, 256, 0, stream>>>(feats, wih_f, b_f, nullptr, nullptr, xgf, NWORD, 2048, 300, 0, 16);
  gemm_bt_kernel<<<32 * 16, 256, 0, stream>>>(feats, wih_b, b_b, nullptr, nullptr, xgb, NWORD, 2048, 300, 0, 16);
  {
    void* args[] = { (void*)&xgf, (void*)&xgb, (void*)&whh_f, (void*)&whh_b,
                     (void*)&lens, (void*)&lstm_o, (void*)&hglob, (void*)&bar };
    hipLaunchCooperativeKernel((void*)lstm_kernel, dim3(LSTM_BLOCKS), dim3(256), args, 0, stream);
  }
  logits_kernel<<<NWORD, 64, 0, stream>>>(lstm_o, out_w, out_b, logits);
  crf_gold_kernel<<<NB, 64, 0, stream>>>(logits, labels, lens, trn, gold);
  crf_norm_kernel<<<NB, 64, 0, stream>>>(logits, lens, trn, gold, loglik);
}

// Round 3
// 1535.256 us; speedup vs baseline: 2.2879x; 1.3303x over previous
//
#include <hip/hip_runtime.h>

#define NB    32
#define SEQ   128
#define WCH   20
#define CED   50
#define NFLT  64
#define WDIM  300
#define HD    512
#define NWORD 4096
#define LPAD  11
#define NEGV  -10000.0f
#define LSTM_BLOCKS 16

typedef float f32x4 __attribute__((ext_vector_type(4)));
typedef __bf16 bf16x8 __attribute__((ext_vector_type(8)));
typedef unsigned short u16x8 __attribute__((ext_vector_type(8)));

static __device__ __forceinline__ unsigned short f2bf(float f) {
  unsigned u = __builtin_bit_cast(unsigned, f);
  u += 0x7fffu + ((u >> 16) & 1u);
  return (unsigned short)(u >> 16);
}
static __device__ __forceinline__ float bf2f(unsigned short s) {
  unsigned u = ((unsigned)s) << 16;
  return __builtin_bit_cast(float, u);
}
static __device__ __forceinline__ float sigf(float x) { return 1.0f / (1.0f + expf(-x)); }
static __device__ __forceinline__ void unpk(unsigned u, float& a, float& b) {
  a = bf2f((unsigned short)(u & 0xffffu));
  b = bf2f((unsigned short)(u >> 16));
}

// ---------------------------------------------------------------- char CNN
__global__ __launch_bounds__(256) void conv_kernel(
    const int* __restrict__ char_ids, const float* __restrict__ char_embed,
    const float* __restrict__ w2, const float* __restrict__ b2,
    const float* __restrict__ w3, const float* __restrict__ b3,
    const float* __restrict__ w4, const float* __restrict__ b4,
    const float* __restrict__ w5, const float* __restrict__ b5,
    float* __restrict__ ch)
{
  __shared__ __align__(16) float xT[CED][WCH];   // transposed: [c][p]
  int wi = blockIdx.x;
  int tid = threadIdx.x;
  for (int e = tid; e < WCH * CED; e += 256) {
    int p = e / CED, c = e - p * CED;
    int cid = char_ids[wi * WCH + p];
    xT[c][p] = char_embed[cid * CED + c];
  }
  __syncthreads();
  int w = tid >> 6, f = tid & 63;      // wave w <-> kernel size k=w+2, lane=filter
  int k = w + 2;
  int P = WCH - k + 1;
  const float* cw = (w == 0) ? w2 : (w == 1) ? w3 : (w == 2) ? w4 : w5;
  const float* cb = (w == 0) ? b2 : (w == 1) ? b3 : (w == 2) ? b4 : b5;
  float acc[19];
  #pragma unroll
  for (int p = 0; p < 19; p++) acc[p] = 0.f;
  for (int c = 0; c < CED; c++) {
    float xr[20];
    const float4* rowp = (const float4*)&xT[c][0];
    #pragma unroll
    for (int q = 0; q < 5; q++) {
      float4 v = rowp[q];
      xr[4*q+0] = v.x; xr[4*q+1] = v.y; xr[4*q+2] = v.z; xr[4*q+3] = v.w;
    }
    #pragma unroll
    for (int dw = 0; dw < 5; dw++) {
      if (dw < k) {
        float wv = cw[(dw * CED + c) * NFLT + f];
        #pragma unroll
        for (int p = 0; p < 19; p++) {
          if (p < P) acc[p] += xr[p + dw] * wv;
        }
      }
    }
  }
  float m = acc[0];
  #pragma unroll
  for (int p = 1; p < 19; p++) if (p < P) m = fmaxf(m, acc[p]);
  ch[wi * 256 + w * 64 + f] = fmaxf(0.f, m + cb[f]);
}

// ---------------------------------------------------------------- word gather
__global__ void gather_word_kernel(const int* __restrict__ token_ids,
                                   const float* __restrict__ word_embed,
                                   float* __restrict__ word_in)
{
  int idx = blockIdx.x * 256 + threadIdx.x;
  if (idx < NWORD * WDIM) {
    int i = idx / WDIM, c = idx - i * WDIM;
    word_in[idx] = word_embed[token_ids[i] * WDIM + c];
  }
}

// ---------------------------------------------------------------- generic MFMA GEMM: C = act(A @ B^T + Cin + bias)
__global__ __launch_bounds__(256) void gemm_bt_kernel(
    const float* __restrict__ A, const float* __restrict__ Bw,
    const float* __restrict__ bias, const float* __restrict__ Cin,
    float* __restrict__ Cout, unsigned short* __restrict__ Cbf,
    int M, int N, int K, int act, int gridN)
{
  __shared__ __align__(16) unsigned short As[128 * 32];
  __shared__ __align__(16) unsigned short Bs[128 * 32];
  int bid = blockIdx.x;
  int tm = bid / gridN, tn = bid - tm * gridN;
  int m0 = tm * 128, n0 = tn * 128;
  int tid = threadIdx.x;
  int lane = tid & 63, w = tid >> 6;
  int wr = (w >> 1) * 64, wc = (w & 1) * 64;
  f32x4 acc[4][4] = {};
  int fr = lane & 15, fk = (lane >> 4) * 8;

  for (int k0 = 0; k0 < K; k0 += 32) {
    __syncthreads();
    #pragma unroll
    for (int i = 0; i < 16; i++) {
      int e = tid + i * 256;
      int r = e >> 5, c = e & 31;
      int kx = k0 + c;
      int ra = m0 + r, rb = n0 + r;
      float av = (kx < K && ra < M) ? A[(size_t)ra * K + kx] : 0.f;
      float bv = (kx < K && rb < N) ? Bw[(size_t)rb * K + kx] : 0.f;
      As[r * 32 + c] = f2bf(av);
      Bs[r * 32 + c] = f2bf(bv);
    }
    __syncthreads();
    bf16x8 a[4], b[4];
    #pragma unroll
    for (int mt = 0; mt < 4; mt++)
      a[mt] = *(const bf16x8*)&As[(wr + mt * 16 + fr) * 32 + fk];
    #pragma unroll
    for (int nt = 0; nt < 4; nt++)
      b[nt] = *(const bf16x8*)&Bs[(wc + nt * 16 + fr) * 32 + fk];
    #pragma unroll
    for (int mt = 0; mt < 4; mt++)
      #pragma unroll
      for (int nt = 0; nt < 4; nt++)
        acc[mt][nt] = __builtin_amdgcn_mfma_f32_16x16x32_bf16(a[mt], b[nt], acc[mt][nt], 0, 0, 0);
  }

  #pragma unroll
  for (int mt = 0; mt < 4; mt++) {
    #pragma unroll
    for (int nt = 0; nt < 4; nt++) {
      #pragma unroll
      for (int j = 0; j < 4; j++) {
        int row = m0 + wr + mt * 16 + (lane >> 4) * 4 + j;
        int col = n0 + wc + nt * 16 + (lane & 15);
        if (row < M && col < N) {
          float v = acc[mt][nt][j];
          if (Cin)  v += Cin[(size_t)row * N + col];
          if (bias) v += bias[col];
          if (act == 1)      v = tanhf(v);
          else if (act == 2) v = sigf(v);
          if (Cbf) Cbf[(size_t)row * N + col] = f2bf(v);
          else     Cout[(size_t)row * N + col] = v;
        }
      }
    }
  }
}

// ---------------------------------------------------------------- gate combine (+ flag reset)
__global__ void feats_kernel(const float* __restrict__ g, const float* __restrict__ word_in,
                             const float* __restrict__ char_in, float* __restrict__ feats,
                             unsigned* __restrict__ flags)
{
  if (blockIdx.x == 0 && threadIdx.x < 32)
    __hip_atomic_store(&flags[threadIdx.x], 0u, __ATOMIC_RELAXED, __HIP_MEMORY_SCOPE_AGENT);
  int idx = blockIdx.x * 256 + threadIdx.x;
  if (idx < NWORD * WDIM) {
    float gg = g[idx];
    feats[idx] = gg * word_in[idx] + (1.f - gg) * char_in[idx];
  }
}

// ---------------------------------------------------------------- bidirectional LSTM (persistent, flag-barrier)
// 16 blocks x 1024 threads: dir = bid>>3, slice = bid&7 (64 hidden units).
// Wave w: gate g=w&3, chunk hc=w>>2. whh slice VGPR-resident as MFMA B-fragments.
// h exchanged via agent-scope (sc1, L3-coherent) atomics; no threadfence anywhere.
__global__ __launch_bounds__(1024, 4) void lstm_kernel(
    const unsigned short* __restrict__ xg_f, const unsigned short* __restrict__ xg_b,
    const float* __restrict__ whh_f, const float* __restrict__ whh_b,
    const int* __restrict__ lens,
    float* __restrict__ lstm_out, unsigned short* __restrict__ h_glob,
    unsigned* __restrict__ flags)
{
  int bid = blockIdx.x;
  int dir = bid >> 3, sl = bid & 7;
  int hs0 = sl << 6;                       // 64 hidden units per block
  int tid = threadIdx.x, lane = tid & 63, w = tid >> 6;
  int g = w & 3, hc = w >> 2;
  int l15 = lane & 15, lhi = lane >> 4;
  const unsigned short* xg = dir ? xg_b : xg_f;
  const float* whh = dir ? whh_b : whh_f;
  unsigned short* hg = h_glob + dir * (2 * NB * HD);
  unsigned* myflags = flags + dir * 16;    // 8 flags per dir, separate 64B lines

  // B-fragments of whh rows [g*512 + hs0 + hc*16 .. +16)
  bf16x8 wf[16];
  {
    const float* src = whh + (size_t)(g * HD + hs0 + hc * 16 + l15) * HD;
    #pragma unroll
    for (int kk = 0; kk < 16; kk++) {
      int kb = kk * 32 + lhi * 8;
      u16x8 t;
      #pragma unroll
      for (int j2 = 0; j2 < 8; j2++) t[j2] = f2bf(src[kb + j2]);
      wf[kk] = __builtin_bit_cast(bf16x8, t);
    }
  }

  __shared__ __align__(16) unsigned short hS[32 * 512];  // staged h, XOR-swizzled 16B chunks
  __shared__ float Gs[NB][260];                          // [batch][gate*64 + hidden-in-block]

  int b = tid >> 5, hp = tid & 31;        // update mapping: batch, hidden pair
  int j0 = 2 * hp, j1 = j0 + 1;
  int mylen = lens[b];
  float c0 = 0.f, c1 = 0.f;
  float hprev0 = 0.f, hprev1 = 0.f;

  for (int s = 0; s < SEQ; s++) {
    int t = dir ? (SEQ - 1 - s) : s;

    if (s > 0) {
      // ---- wait for all 8 producers of this dir to publish h(s-1)
      if (tid == 0) {
        unsigned long long* fp = (unsigned long long*)myflags;
        for (;;) {
          unsigned long long f0 = __hip_atomic_load(fp + 0, __ATOMIC_RELAXED, __HIP_MEMORY_SCOPE_AGENT);
          unsigned long long f1 = __hip_atomic_load(fp + 1, __ATOMIC_RELAXED, __HIP_MEMORY_SCOPE_AGENT);
          unsigned long long f2 = __hip_atomic_load(fp + 2, __ATOMIC_RELAXED, __HIP_MEMORY_SCOPE_AGENT);
          unsigned long long f3 = __hip_atomic_load(fp + 3, __ATOMIC_RELAXED, __HIP_MEMORY_SCOPE_AGENT);
          unsigned mn = (unsigned)f0;
          mn = min(mn, (unsigned)(f0 >> 32));
          mn = min(mn, (unsigned)f1); mn = min(mn, (unsigned)(f1 >> 32));
          mn = min(mn, (unsigned)f2); mn = min(mn, (unsigned)(f2 >> 32));
          mn = min(mn, (unsigned)f3); mn = min(mn, (unsigned)(f3 >> 32));
          if (mn >= (unsigned)s) break;
          __builtin_amdgcn_s_sleep(1);
        }
      }
      __syncthreads();
      // ---- stage h(s-1) -> LDS (bypass loads, 32B/thread), swizzled
      {
        unsigned long long* hq = (unsigned long long*)(hg + (s & 1) * (NB * HD));
        unsigned long long v0 = __hip_atomic_load(hq + tid * 4 + 0, __ATOMIC_RELAXED, __HIP_MEMORY_SCOPE_AGENT);
        unsigned long long v1 = __hip_atomic_load(hq + tid * 4 + 1, __ATOMIC_RELAXED, __HIP_MEMORY_SCOPE_AGENT);
        unsigned long long v2 = __hip_atomic_load(hq + tid * 4 + 2, __ATOMIC_RELAXED, __HIP_MEMORY_SCOPE_AGENT);
        unsigned long long v3 = __hip_atomic_load(hq + tid * 4 + 3, __ATOMIC_RELAXED, __HIP_MEMORY_SCOPE_AGENT);
        int row = tid >> 5;
        int colb = (tid & 31) * 32;
        unsigned sw = (unsigned)((row & 7) << 4);
        char* base = (char*)hS + row * 1024;
        uint4 q0, q1;
        q0.x = (unsigned)v0; q0.y = (unsigned)(v0 >> 32); q0.z = (unsigned)v1; q0.w = (unsigned)(v1 >> 32);
        q1.x = (unsigned)v2; q1.y = (unsigned)(v2 >> 32); q1.z = (unsigned)v3; q1.w = (unsigned)(v3 >> 32);
        *(uint4*)(base + ((unsigned)colb ^ sw)) = q0;
        *(uint4*)(base + ((unsigned)(colb + 16) ^ sw)) = q1;
      }
    }

    // ---- issue xg loads early (latency hides under MFMA)
    unsigned xpi, xpf, xpg, xpo;
    {
      const unsigned* x32 = (const unsigned*)xg;
      size_t base2 = (((size_t)(b * SEQ + t)) * 2048 + hs0 + j0) >> 1;
      xpi = x32[base2 + 0];
      xpf = x32[base2 + 256];
      xpg = x32[base2 + 512];
      xpo = x32[base2 + 768];
    }

    f32x4 acc0 = {0.f, 0.f, 0.f, 0.f};
    f32x4 acc1 = {0.f, 0.f, 0.f, 0.f};
    if (s > 0) {
      __syncthreads();
      #pragma unroll
      for (int kk = 0; kk < 16; kk++) {
        int cb = kk * 64 + lhi * 16;
        int r0 = l15, r1 = 16 + l15;
        unsigned sw = (unsigned)((r0 & 7) << 4);
        bf16x8 a0 = *(const bf16x8*)((const char*)hS + ((unsigned)(r0 * 1024 + cb) ^ sw));
        bf16x8 a1 = *(const bf16x8*)((const char*)hS + ((unsigned)(r1 * 1024 + cb) ^ sw));
        acc0 = __builtin_amdgcn_mfma_f32_16x16x32_bf16(a0, wf[kk], acc0, 0, 0, 0);
        acc1 = __builtin_amdgcn_mfma_f32_16x16x32_bf16(a1, wf[kk], acc1, 0, 0, 0);
      }
    }
    #pragma unroll
    for (int j2 = 0; j2 < 4; j2++) {
      int b0 = lhi * 4 + j2;
      Gs[b0][g * 64 + hc * 16 + l15] = acc0[j2];
      Gs[16 + b0][g * 64 + hc * 16 + l15] = acc1[j2];
    }
    __syncthreads();

    float xi0, xi1, xf0, xf1, xG0, xG1, xo0, xo1;
    unpk(xpi, xi0, xi1); unpk(xpf, xf0, xf1); unpk(xpg, xG0, xG1); unpk(xpo, xo0, xo1);

    float i0 = sigf(xi0 + Gs[b][j0]),        i1 = sigf(xi1 + Gs[b][j1]);
    float f0 = sigf(xf0 + Gs[b][64 + j0]),   f1 = sigf(xf1 + Gs[b][64 + j1]);
    float g0 = tanhf(xG0 + Gs[b][128 + j0]), g1 = tanhf(xG1 + Gs[b][128 + j1]);
    float o0 = sigf(xo0 + Gs[b][192 + j0]),  o1 = sigf(xo1 + Gs[b][192 + j1]);
    float cn0 = f0 * c0 + i0 * g0;
    float cn1 = f1 * c1 + i1 * g1;
    float hn0 = o0 * tanhf(cn0);
    float hn1 = o1 * tanhf(cn1);

    bool mk = (t < mylen);
    if (mk) { c0 = cn0; c1 = cn1; }
    float hk0 = mk ? hn0 : hprev0, hk1 = mk ? hn1 : hprev1;
    hprev0 = hk0; hprev1 = hk1;

    // publish h (bypass store, coherent at L3)
    {
      unsigned* hdst32 = (unsigned*)(hg + ((s & 1) ^ 1) * (NB * HD));
      unsigned pk = (unsigned)f2bf(hk0) | ((unsigned)f2bf(hk1) << 16);
      __hip_atomic_store(&hdst32[(b * HD + hs0 + j0) >> 1], pk, __ATOMIC_RELAXED, __HIP_MEMORY_SCOPE_AGENT);
    }
    size_t obase = ((size_t)(b * SEQ + t)) * 1024 + dir * HD + hs0 + j0;
    *(float2*)&lstm_out[obase] = make_float2(mk ? hn0 : 0.f, mk ? hn1 : 0.f);

    __syncthreads();   // drains every wave's vmcnt -> h at L3
    if (tid == 0)
      __hip_atomic_store(&myflags[sl], (unsigned)(s + 1), __ATOMIC_RELAXED, __HIP_MEMORY_SCOPE_AGENT);
  }
}

// ---------------------------------------------------------------- output projection + NEG pads
__global__ __launch_bounds__(64) void logits_kernel(
    const float* __restrict__ lstm_out, const float* __restrict__ out_w,
    const float* __restrict__ out_b, float* __restrict__ lg)
{
  int rw = blockIdx.x, j = threadIdx.x;
  const float* row = lstm_out + (size_t)rw * 1024;
  float s[9];
  #pragma unroll
  for (int l = 0; l < 9; l++) s[l] = 0.f;
  for (int e = j; e < 1024; e += 64) {
    float x = row[e];
    #pragma unroll
    for (int l = 0; l < 9; l++) s[l] += x * out_w[l * 1024 + e];
  }
  #pragma unroll
  for (int l = 0; l < 9; l++) {
    #pragma unroll
    for (int off = 32; off > 0; off >>= 1) s[l] += __shfl_xor(s[l], off);
  }
  float v = NEGV;
  if (j < 9) {
    float r = (j==0)?s[0]:(j==1)?s[1]:(j==2)?s[2]:(j==3)?s[3]:(j==4)?s[4]:
              (j==5)?s[5]:(j==6)?s[6]:(j==7)?s[7]:s[8];
    v = r + out_b[j];
  }
  if (j < LPAD) lg[(size_t)rw * LPAD + j] = v;
}

// ---------------------------------------------------------------- CRF gold score
__global__ __launch_bounds__(64) void crf_gold_kernel(
    const float* __restrict__ lg, const int* __restrict__ labels,
    const int* __restrict__ lens, const float* __restrict__ trn, float* __restrict__ gold)
{
  int b = blockIdx.x, j = threadIdx.x;
  int len = lens[b];
  const int* lab = labels + b * SEQ;
  const float* l0 = lg + (size_t)b * SEQ * LPAD;
  float s = 0.f;
  for (int t = j; t < SEQ; t += 64) {
    if (t < len) {
      s += l0[t * LPAD + lab[t]];
      if (t >= 1) s += trn[lab[t] * LPAD + lab[t - 1]];
    }
  }
  #pragma unroll
  for (int off = 32; off > 0; off >>= 1) s += __shfl_xor(s, off);
  if (j == 0) {
    s += trn[lab[0] * LPAD + 9];
    s += trn[10 * LPAD + lab[len - 1]];
    gold[b] = s;
  }
}

// ---------------------------------------------------------------- CRF norm + final loglik
__global__ __launch_bounds__(64) void crf_norm_kernel(
    const float* __restrict__ lg, const int* __restrict__ lens,
    const float* __restrict__ trn, const float* __restrict__ gold, float* __restrict__ out_ll)
{
  int b = blockIdx.x, i = threadIdx.x;
  int len = lens[b];
  const float* l0 = lg + (size_t)b * SEQ * LPAD;
  bool act = (i < LPAD);
  float trow[LPAD];
  #pragma unroll
  for (int jj = 0; jj < LPAD; jj++) trow[jj] = act ? trn[i * LPAD + jj] : 0.f;
  float alpha = act ? (l0[i] + trow[9]) : -1e30f;

  for (int t = 1; t < SEQ; t++) {
    float vj[LPAD];
    #pragma unroll
    for (int jj = 0; jj < LPAD; jj++) vj[jj] = __shfl(alpha, jj) + trow[jj];
    float mx = vj[0];
    #pragma unroll
    for (int jj = 1; jj < LPAD; jj++) mx = fmaxf(mx, vj[jj]);
    float sum = 0.f;
    #pragma unroll
    for (int jj = 0; jj < LPAD; jj++) sum += expf(vj[jj] - mx);
    float lgv = act ? l0[t * LPAD + i] : 0.f;
    float nw = mx + logf(sum) + lgv;
    if (act && t < len) alpha = nw;
  }
  float vj[LPAD];
  #pragma unroll
  for (int jj = 0; jj < LPAD; jj++) vj[jj] = __shfl(alpha, jj) + trn[10 * LPAD + jj];
  float mx = vj[0];
  #pragma unroll
  for (int jj = 1; jj < LPAD; jj++) mx = fmaxf(mx, vj[jj]);
  float sum = 0.f;
  #pragma unroll
  for (int jj = 0; jj < LPAD; jj++) sum += expf(vj[jj] - mx);
  if (i == 0) out_ll[b] = gold[b] - (mx + logf(sum));
}

// ================================================================ launch
extern "C" void kernel_launch(void* const* d_in, const int* in_sizes, int n_in,
                              void* d_out, int out_size, void* d_ws, size_t ws_size,
                              hipStream_t stream)
{
  (void)in_sizes; (void)n_in; (void)out_size; (void)ws_size;
  const int*   token_ids = (const int*)d_in[0];
  const int*   char_ids  = (const int*)d_in[1];
  const int*   lens      = (const int*)d_in[2];
  const int*   labels    = (const int*)d_in[3];
  const float* word_embed= (const float*)d_in[4];
  const float* char_embed= (const float*)d_in[5];
  const float* w2 = (const float*)d_in[6];  const float* cb2 = (const float*)d_in[7];
  const float* w3 = (const float*)d_in[8];  const float* cb3 = (const float*)d_in[9];
  const float* w4 = (const float*)d_in[10]; const float* cb4 = (const float*)d_in[11];
  const float* w5 = (const float*)d_in[12]; const float* cb5 = (const float*)d_in[13];
  const float* ff_w = (const float*)d_in[14]; const float* ff_b = (const float*)d_in[15];
  const float* wgate_w = (const float*)d_in[16];
  const float* cgate_w = (const float*)d_in[17];
  const float* gate_w  = (const float*)d_in[18];
  const float* wih_f = (const float*)d_in[19]; const float* whh_f = (const float*)d_in[20];
  const float* b_f   = (const float*)d_in[21];
  const float* wih_b = (const float*)d_in[22]; const float* whh_b = (const float*)d_in[23];
  const float* b_b   = (const float*)d_in[24];
  const float* out_w = (const float*)d_in[25]; const float* out_b = (const float*)d_in[26];
  const float* trn   = (const float*)d_in[27];

  char* ws = (char*)d_ws;
  size_t off = 0;
  auto alloc = [&](size_t bytes) { void* p = ws + off; off += (bytes + 255) & ~(size_t)255; return p; };
  float* ch       = (float*)alloc((size_t)NWORD * 256 * 4);
  float* word_in  = (float*)alloc((size_t)NWORD * WDIM * 4);
  float* char_in  = (float*)alloc((size_t)NWORD * WDIM * 4);
  float* t1       = (float*)alloc((size_t)NWORD * WDIM * 4);
  float* gbuf     = (float*)alloc((size_t)NWORD * WDIM * 4);
  float* feats    = (float*)alloc((size_t)NWORD * WDIM * 4);
  unsigned short* xgf = (unsigned short*)alloc((size_t)NWORD * 2048 * 2);
  unsigned short* xgb = (unsigned short*)alloc((size_t)NWORD * 2048 * 2);
  float* lstm_o   = (float*)alloc((size_t)NWORD * 1024 * 4);
  unsigned short* hglob = (unsigned short*)alloc((size_t)2 * 2 * NB * HD * 2);
  float* gold     = (float*)alloc((size_t)NB * 4);
  unsigned* flags = (unsigned*)alloc(256);

  float* outp   = (float*)d_out;
  float* loglik = outp;
  float* logits = outp + NB;

  conv_kernel<<<NWORD, 256, 0, stream>>>(char_ids, char_embed, w2, cb2, w3, cb3, w4, cb4, w5, cb5, ch);
  gather_word_kernel<<<(NWORD * WDIM + 255) / 256, 256, 0, stream>>>(token_ids, word_embed, word_in);
  gemm_bt_kernel<<<32 * 3, 256, 0, stream>>>(ch, ff_w, ff_b, nullptr, char_in, nullptr, NWORD, 300, 256, 0, 3);
  gemm_bt_kernel<<<32 * 3, 256, 0, stream>>>(word_in, wgate_w, nullptr, nullptr, t1, nullptr, NWORD, 300, 300, 0, 3);
  gemm_bt_kernel<<<32 * 3, 256, 0, stream>>>(char_in, cgate_w, nullptr, t1, t1, nullptr, NWORD, 300, 300, 1, 3);
  gemm_bt_kernel<<<32 * 3, 256, 0, stream>>>(t1, gate_w, nullptr, nullptr, gbuf, nullptr, NWORD, 300, 300, 2, 3);
  feats_kernel<<<(NWORD * WDIM + 255) / 256, 256, 0, stream>>>(gbuf, word_in, char_in, feats, flags);
  gemm_bt_kernel<<<32 * 16, 256, 0, stream>>>(feats, wih_f, b_f, nullptr, nullptr, xgf, NWORD, 2048, 300, 0, 16);
  gemm_bt_kernel<<<32 * 16, 256, 0, stream>>>(feats, wih_b, b_b, nullptr, nullptr, xgb, NWORD, 2048, 300, 0, 16);
  {
    void* args[] = { (void*)&xgf, (void*)&xgb, (void*)&whh_f, (void*)&whh_b,
                     (void*)&lens, (void*)&lstm_o, (void*)&hglob, (void*)&flags };
    hipLaunchCooperativeKernel((void*)lstm_kernel, dim3(LSTM_BLOCKS), dim3(1024), args, 0, stream);
  }
  logits_kernel<<<NWORD, 64, 0, stream>>>(lstm_o, out_w, out_b, logits);
  crf_gold_kernel<<<NB, 64, 0, stream>>>(logits, labels, lens, trn, gold);
  crf_norm_kernel<<<NB, 64, 0, stream>>>(logits, lens, trn, gold, loglik);
}

// Round 4
// 1302.866 us; speedup vs baseline: 2.6960x; 1.1784x over previous
//
#include <hip/hip_runtime.h>

#define NB    32
#define SEQ   128
#define WCH   20
#define CED   50
#define NFLT  64
#define WDIM  300
#define HD    512
#define NWORD 4096
#define LPAD  11
#define NEGV  -10000.0f
#define LSTM_BLOCKS 16

typedef float f32x4 __attribute__((ext_vector_type(4)));
typedef float f32x16 __attribute__((ext_vector_type(16)));
typedef __bf16 bf16x8 __attribute__((ext_vector_type(8)));
typedef unsigned short u16x8 __attribute__((ext_vector_type(8)));
typedef unsigned short u16x4 __attribute__((ext_vector_type(4)));
typedef unsigned long long ull;

static __device__ __forceinline__ unsigned short f2bf(float f) {
  unsigned u = __builtin_bit_cast(unsigned, f);
  u += 0x7fffu + ((u >> 16) & 1u);
  return (unsigned short)(u >> 16);
}
static __device__ __forceinline__ float bf2f(unsigned short s) {
  unsigned u = ((unsigned)s) << 16;
  return __builtin_bit_cast(float, u);
}
static __device__ __forceinline__ float sigf(float x) { return 1.0f / (1.0f + expf(-x)); }

// ---------------------------------------------------------------- char CNN
__global__ __launch_bounds__(256) void conv_kernel(
    const int* __restrict__ char_ids, const float* __restrict__ char_embed,
    const float* __restrict__ w2, const float* __restrict__ b2,
    const float* __restrict__ w3, const float* __restrict__ b3,
    const float* __restrict__ w4, const float* __restrict__ b4,
    const float* __restrict__ w5, const float* __restrict__ b5,
    float* __restrict__ ch)
{
  __shared__ __align__(16) float xT[CED][WCH];
  int wi = blockIdx.x;
  int tid = threadIdx.x;
  for (int e = tid; e < WCH * CED; e += 256) {
    int p = e / CED, c = e - p * CED;
    int cid = char_ids[wi * WCH + p];
    xT[c][p] = char_embed[cid * CED + c];
  }
  __syncthreads();
  int w = tid >> 6, f = tid & 63;
  int k = w + 2;
  int P = WCH - k + 1;
  const float* cw = (w == 0) ? w2 : (w == 1) ? w3 : (w == 2) ? w4 : w5;
  const float* cb = (w == 0) ? b2 : (w == 1) ? b3 : (w == 2) ? b4 : b5;
  float acc[19];
  #pragma unroll
  for (int p = 0; p < 19; p++) acc[p] = 0.f;
  for (int c = 0; c < CED; c++) {
    float xr[20];
    const float4* rowp = (const float4*)&xT[c][0];
    #pragma unroll
    for (int q = 0; q < 5; q++) {
      float4 v = rowp[q];
      xr[4*q+0] = v.x; xr[4*q+1] = v.y; xr[4*q+2] = v.z; xr[4*q+3] = v.w;
    }
    #pragma unroll
    for (int dw = 0; dw < 5; dw++) {
      if (dw < k) {
        float wv = cw[(dw * CED + c) * NFLT + f];
        #pragma unroll
        for (int p = 0; p < 19; p++) {
          if (p < P) acc[p] += xr[p + dw] * wv;
        }
      }
    }
  }
  float m = acc[0];
  #pragma unroll
  for (int p = 1; p < 19; p++) if (p < P) m = fmaxf(m, acc[p]);
  ch[wi * 256 + w * 64 + f] = fmaxf(0.f, m + cb[f]);
}

// ---------------------------------------------------------------- word gather
__global__ void gather_word_kernel(const int* __restrict__ token_ids,
                                   const float* __restrict__ word_embed,
                                   float* __restrict__ word_in)
{
  int idx = blockIdx.x * 256 + threadIdx.x;
  if (idx < NWORD * WDIM) {
    int i = idx / WDIM, c = idx - i * WDIM;
    word_in[idx] = word_embed[token_ids[i] * WDIM + c];
  }
}

// ---------------------------------------------------------------- generic MFMA GEMM: C = act(A @ B^T + Cin + bias)
__global__ __launch_bounds__(256) void gemm_bt_kernel(
    const float* __restrict__ A, const float* __restrict__ Bw,
    const float* __restrict__ bias, const float* __restrict__ Cin,
    float* __restrict__ Cout, unsigned short* __restrict__ Cbf,
    int M, int N, int K, int act, int gridN)
{
  __shared__ __align__(16) unsigned short As[128 * 32];
  __shared__ __align__(16) unsigned short Bs[128 * 32];
  int bid = blockIdx.x;
  int tm = bid / gridN, tn = bid - tm * gridN;
  int m0 = tm * 128, n0 = tn * 128;
  int tid = threadIdx.x;
  int lane = tid & 63, w = tid >> 6;
  int wr = (w >> 1) * 64, wc = (w & 1) * 64;
  f32x4 acc[4][4] = {};
  int fr = lane & 15, fk = (lane >> 4) * 8;

  for (int k0 = 0; k0 < K; k0 += 32) {
    __syncthreads();
    #pragma unroll
    for (int i = 0; i < 4; i++) {
      int idx = tid + i * 256;          // float4 slot 0..1023
      int r = idx >> 3, c4 = idx & 7;
      int kx = k0 + c4 * 4;
      int ra = m0 + r, rb = n0 + r;
      f32x4 av = {0.f,0.f,0.f,0.f}, bv = {0.f,0.f,0.f,0.f};
      if (kx < K) {                     // all K are multiples of 4
        if (ra < M) av = *(const f32x4*)&A[(size_t)ra * K + kx];
        if (rb < N) bv = *(const f32x4*)&Bw[(size_t)rb * K + kx];
      }
      u16x4 ap, bp;
      #pragma unroll
      for (int j = 0; j < 4; j++) { ap[j] = f2bf(av[j]); bp[j] = f2bf(bv[j]); }
      *(u16x4*)&As[r * 32 + c4 * 4] = ap;
      *(u16x4*)&Bs[r * 32 + c4 * 4] = bp;
    }
    __syncthreads();
    bf16x8 a[4], b[4];
    #pragma unroll
    for (int mt = 0; mt < 4; mt++)
      a[mt] = *(const bf16x8*)&As[(wr + mt * 16 + fr) * 32 + fk];
    #pragma unroll
    for (int nt = 0; nt < 4; nt++)
      b[nt] = *(const bf16x8*)&Bs[(wc + nt * 16 + fr) * 32 + fk];
    #pragma unroll
    for (int mt = 0; mt < 4; mt++)
      #pragma unroll
      for (int nt = 0; nt < 4; nt++)
        acc[mt][nt] = __builtin_amdgcn_mfma_f32_16x16x32_bf16(a[mt], b[nt], acc[mt][nt], 0, 0, 0);
  }

  #pragma unroll
  for (int mt = 0; mt < 4; mt++) {
    #pragma unroll
    for (int nt = 0; nt < 4; nt++) {
      #pragma unroll
      for (int j = 0; j < 4; j++) {
        int row = m0 + wr + mt * 16 + (lane >> 4) * 4 + j;
        int col = n0 + wc + nt * 16 + (lane & 15);
        if (row < M && col < N) {
          float v = acc[mt][nt][j];
          if (Cin)  v += Cin[(size_t)row * N + col];
          if (bias) v += bias[col];
          if (act == 1)      v = tanhf(v);
          else if (act == 2) v = sigf(v);
          if (Cbf) Cbf[(size_t)row * N + col] = f2bf(v);
          else     Cout[(size_t)row * N + col] = v;
        }
      }
    }
  }
}

// ---------------------------------------------------------------- gate combine (+ flag reset)
__global__ void feats_kernel(const float* __restrict__ g, const float* __restrict__ word_in,
                             const float* __restrict__ char_in, float* __restrict__ feats,
                             unsigned* __restrict__ flags)
{
  if (blockIdx.x == 0 && threadIdx.x < 32)
    __hip_atomic_store(&flags[threadIdx.x], 0u, __ATOMIC_RELAXED, __HIP_MEMORY_SCOPE_AGENT);
  int idx = blockIdx.x * 256 + threadIdx.x;
  if (idx < NWORD * WDIM) {
    float gg = g[idx];
    feats[idx] = gg * word_in[idx] + (1.f - gg) * char_in[idx];
  }
}

// ---------------------------------------------------------------- bidirectional LSTM (persistent, flag-barrier)
// 16 blocks x 512 threads: dir = bid>>3, slice = bid&7 (64 hidden units).
// Wave w: gate g=w&3, 32-col chunk hc=w>>2. whh slice VGPR-resident as 32x32x16 B-fragments.
// h exchanged via agent-scope (L3-coherent) atomics; no threadfence anywhere.
// hS layout is fragment-major: block (kk,e) at (kk*2+e)*512B holds h[row][kk*16+e*8..+8]
// at rowS = row ^ ((kk>>1)&7)  -> bank-uniform for both staging writes and fragment reads.
__global__ __launch_bounds__(512, 2) void lstm_kernel(
    const unsigned short* __restrict__ xg_f, const unsigned short* __restrict__ xg_b,
    const float* __restrict__ whh_f, const float* __restrict__ whh_b,
    const int* __restrict__ lens,
    float* __restrict__ lstm_out, unsigned short* __restrict__ h_glob,
    unsigned* __restrict__ flags)
{
  int bid = blockIdx.x;
  int dir = bid >> 3, sl = bid & 7;
  int hs0 = sl << 6;                       // 64 hidden units per block
  int tid = threadIdx.x, lane = tid & 63, w = tid >> 6;
  int g = w & 3, hc = w >> 2;              // gate, 32-unit chunk
  int l31 = lane & 31, le = lane >> 5;     // A-row / D-col, k-half
  const unsigned short* xg = dir ? xg_b : xg_f;
  const float* whh = dir ? whh_b : whh_f;
  unsigned short* hg = h_glob + dir * (2 * NB * HD);
  unsigned* myflags = flags + dir * 16;

  // B-fragments: wf[kk] = whh rows (units) g*512+hs0+hc*32+l31, k = kk*16 + le*8 + j
  bf16x8 wf[32];
  {
    const float* src = whh + (size_t)(g * HD + hs0 + hc * 32 + l31) * HD + le * 8;
    #pragma unroll
    for (int kk = 0; kk < 32; kk++) {
      u16x8 tv;
      #pragma unroll
      for (int j = 0; j < 8; j++) tv[j] = f2bf(src[kk * 16 + j]);
      wf[kk] = __builtin_bit_cast(bf16x8, tv);
    }
  }

  __shared__ __align__(16) unsigned short hS[16384];   // 32KB fragment-major
  __shared__ float Gs[NB][260];                        // [batch][gate*64 + unit]

  int b = tid >> 4;                        // batch
  int u = (tid & 15) << 2;                 // 4 units per thread
  int srow = tid >> 4, sq = tid & 15;      // staging mapping
  int mylen = lens[b];
  float c4[4] = {0.f,0.f,0.f,0.f}, hp4[4] = {0.f,0.f,0.f,0.f};

  // preload xg for s=0
  ull xq0, xq1, xq2, xq3;
  {
    int t0 = dir ? (SEQ - 1) : 0;
    const ull* xp = (const ull*)&xg[((size_t)(b * SEQ + t0)) * 2048 + hs0 + u];
    xq0 = xp[0]; xq1 = xp[128]; xq2 = xp[256]; xq3 = xp[384];
  }

  for (int s = 0; s < SEQ; s++) {
    int t = dir ? (SEQ - 1 - s) : s;
    f32x16 acc0 = {}, acc1 = {};

    if (s > 0) {
      // ---- wait for all 8 producers of this dir to publish h(s-1)
      if (tid == 0) {
        const ull* fp = (const ull*)myflags;
        for (;;) {
          ull f0 = __hip_atomic_load(fp + 0, __ATOMIC_RELAXED, __HIP_MEMORY_SCOPE_AGENT);
          ull f1 = __hip_atomic_load(fp + 1, __ATOMIC_RELAXED, __HIP_MEMORY_SCOPE_AGENT);
          ull f2 = __hip_atomic_load(fp + 2, __ATOMIC_RELAXED, __HIP_MEMORY_SCOPE_AGENT);
          ull f3 = __hip_atomic_load(fp + 3, __ATOMIC_RELAXED, __HIP_MEMORY_SCOPE_AGENT);
          unsigned mn = (unsigned)f0;
          mn = min(mn, (unsigned)(f0 >> 32));
          mn = min(mn, (unsigned)f1); mn = min(mn, (unsigned)(f1 >> 32));
          mn = min(mn, (unsigned)f2); mn = min(mn, (unsigned)(f2 >> 32));
          mn = min(mn, (unsigned)f3); mn = min(mn, (unsigned)(f3 >> 32));
          if (mn >= (unsigned)s) break;
          __builtin_amdgcn_s_sleep(1);
        }
      }
      __syncthreads();                       // B1
      // ---- stage h(s-1) -> LDS, fragment-major (64B/thread)
      {
        const ull* hq = (const ull*)(hg + (s & 1) * (NB * HD));
        ull v[8];
        #pragma unroll
        for (int i = 0; i < 8; i++)
          v[i] = __hip_atomic_load(hq + srow * 128 + sq * 8 + i, __ATOMIC_RELAXED, __HIP_MEMORY_SCOPE_AGENT);
        int rs = ((srow ^ (sq & 7)) & 31) << 4;
        #pragma unroll
        for (int e2 = 0; e2 < 4; e2++) {
          int kk = 2 * sq + (e2 >> 1), e = e2 & 1;
          uint4 qv;
          qv.x = (unsigned)v[2*e2];     qv.y = (unsigned)(v[2*e2] >> 32);
          qv.z = (unsigned)v[2*e2+1];   qv.w = (unsigned)(v[2*e2+1] >> 32);
          *(uint4*)((char*)hS + (((kk * 2 + e) << 9) + rs)) = qv;
        }
      }
      __syncthreads();                       // B2
      // ---- MFMA: acc[batch][unit] += h(s-1) @ whh^T
      #pragma unroll
      for (int kk = 0; kk < 32; kk += 2) {
        int rs = ((l31 ^ ((kk >> 1) & 7)) & 31) << 4;
        int a0off = ((kk * 2 + le) << 9) + rs;
        int a1off = ((kk * 2 + 2 + le) << 9) + rs;
        bf16x8 a0 = *(const bf16x8*)((const char*)hS + a0off);
        bf16x8 a1 = *(const bf16x8*)((const char*)hS + a1off);
        acc0 = __builtin_amdgcn_mfma_f32_32x32x16_bf16(a0, wf[kk], acc0, 0, 0, 0);
        acc1 = __builtin_amdgcn_mfma_f32_32x32x16_bf16(a1, wf[kk+1], acc1, 0, 0, 0);
      }
    }

    // ---- scatter gate pre-activations to Gs
    #pragma unroll
    for (int r = 0; r < 16; r++) {
      int bb = (r & 3) + 8 * (r >> 2) + 4 * le;
      Gs[bb][g * 64 + hc * 32 + l31] = acc0[r] + acc1[r];
    }
    __syncthreads();                         // B3

    // ---- state update: 4 units per thread
    f32x4 gi  = *(const f32x4*)&Gs[b][u];
    f32x4 gfv = *(const f32x4*)&Gs[b][64 + u];
    f32x4 ggv = *(const f32x4*)&Gs[b][128 + u];
    f32x4 gov = *(const f32x4*)&Gs[b][192 + u];
    bool mk = (t < mylen);
    f32x4 outv;
    ull hpk = 0;
    #pragma unroll
    for (int j = 0; j < 4; j++) {
      float xi = bf2f((unsigned short)(xq0 >> (16*j)));
      float xf = bf2f((unsigned short)(xq1 >> (16*j)));
      float xG = bf2f((unsigned short)(xq2 >> (16*j)));
      float xo = bf2f((unsigned short)(xq3 >> (16*j)));
      float iv = sigf(xi + gi[j]);
      float fv = sigf(xf + gfv[j]);
      float Gv = tanhf(xG + ggv[j]);
      float ov = sigf(xo + gov[j]);
      float cn = fv * c4[j] + iv * Gv;
      float hn = ov * tanhf(cn);
      if (mk) c4[j] = cn;
      float hk = mk ? hn : hp4[j];
      hp4[j] = hk;
      outv[j] = mk ? hn : 0.f;
      hpk |= ((ull)f2bf(hk)) << (16*j);
    }
    size_t obase = ((size_t)(b * SEQ + t)) * 1024 + dir * HD + hs0 + u;
    *(f32x4*)&lstm_out[obase] = outv;
    {
      ull* hd = (ull*)(hg + ((s & 1) ^ 1) * (NB * HD));
      __hip_atomic_store(&hd[(b * HD + hs0 + u) >> 2], hpk, __ATOMIC_RELAXED, __HIP_MEMORY_SCOPE_AGENT);
    }

    __syncthreads();                         // B4: drains all waves' stores to L3
    if (tid == 0)
      __hip_atomic_store(&myflags[sl], (unsigned)(s + 1), __ATOMIC_RELAXED, __HIP_MEMORY_SCOPE_AGENT);

    // ---- prefetch next-step xg; drains at B1 in parallel with the spin
    if (s + 1 < SEQ) {
      int tn = dir ? (SEQ - 2 - s) : (s + 1);
      const ull* xp = (const ull*)&xg[((size_t)(b * SEQ + tn)) * 2048 + hs0 + u];
      xq0 = xp[0]; xq1 = xp[128]; xq2 = xp[256]; xq3 = xp[384];
    }
  }
}

// ---------------------------------------------------------------- output projection + NEG pads
__global__ __launch_bounds__(64) void logits_kernel(
    const float* __restrict__ lstm_out, const float* __restrict__ out_w,
    const float* __restrict__ out_b, float* __restrict__ lg)
{
  int rw = blockIdx.x, j = threadIdx.x;
  const float* row = lstm_out + (size_t)rw * 1024;
  float s[9];
  #pragma unroll
  for (int l = 0; l < 9; l++) s[l] = 0.f;
  for (int e = j; e < 1024; e += 64) {
    float x = row[e];
    #pragma unroll
    for (int l = 0; l < 9; l++) s[l] += x * out_w[l * 1024 + e];
  }
  #pragma unroll
  for (int l = 0; l < 9; l++) {
    #pragma unroll
    for (int off = 32; off > 0; off >>= 1) s[l] += __shfl_xor(s[l], off);
  }
  float v = NEGV;
  if (j < 9) {
    float r = (j==0)?s[0]:(j==1)?s[1]:(j==2)?s[2]:(j==3)?s[3]:(j==4)?s[4]:
              (j==5)?s[5]:(j==6)?s[6]:(j==7)?s[7]:s[8];
    v = r + out_b[j];
  }
  if (j < LPAD) lg[(size_t)rw * LPAD + j] = v;
}

// ---------------------------------------------------------------- CRF gold score
__global__ __launch_bounds__(64) void crf_gold_kernel(
    const float* __restrict__ lg, const int* __restrict__ labels,
    const int* __restrict__ lens, const float* __restrict__ trn, float* __restrict__ gold)
{
  int b = blockIdx.x, j = threadIdx.x;
  int len = lens[b];
  const int* lab = labels + b * SEQ;
  const float* l0 = lg + (size_t)b * SEQ * LPAD;
  float s = 0.f;
  for (int t = j; t < SEQ; t += 64) {
    if (t < len) {
      s += l0[t * LPAD + lab[t]];
      if (t >= 1) s += trn[lab[t] * LPAD + lab[t - 1]];
    }
  }
  #pragma unroll
  for (int off = 32; off > 0; off >>= 1) s += __shfl_xor(s, off);
  if (j == 0) {
    s += trn[lab[0] * LPAD + 9];
    s += trn[10 * LPAD + lab[len - 1]];
    gold[b] = s;
  }
}

// ---------------------------------------------------------------- CRF norm + final loglik
__global__ __launch_bounds__(64) void crf_norm_kernel(
    const float* __restrict__ lg, const int* __restrict__ lens,
    const float* __restrict__ trn, const float* __restrict__ gold, float* __restrict__ out_ll)
{
  int b = blockIdx.x, i = threadIdx.x;
  int len = lens[b];
  const float* l0 = lg + (size_t)b * SEQ * LPAD;
  bool act = (i < LPAD);
  float trow[LPAD];
  #pragma unroll
  for (int jj = 0; jj < LPAD; jj++) trow[jj] = act ? trn[i * LPAD + jj] : 0.f;
  float alpha = act ? (l0[i] + trow[9]) : -1e30f;

  for (int t = 1; t < SEQ; t++) {
    float vj[LPAD];
    #pragma unroll
    for (int jj = 0; jj < LPAD; jj++) vj[jj] = __shfl(alpha, jj) + trow[jj];
    float mx = vj[0];
    #pragma unroll
    for (int jj = 1; jj < LPAD; jj++) mx = fmaxf(mx, vj[jj]);
    float sum = 0.f;
    #pragma unroll
    for (int jj = 0; jj < LPAD; jj++) sum += expf(vj[jj] - mx);
    float lgv = act ? l0[t * LPAD + i] : 0.f;
    float nw = mx + logf(sum) + lgv;
    if (act && t < len) alpha = nw;
  }
  float vj[LPAD];
  #pragma unroll
  for (int jj = 0; jj < LPAD; jj++) vj[jj] = __shfl(alpha, jj) + trn[10 * LPAD + jj];
  float mx = vj[0];
  #pragma unroll
  for (int jj = 1; jj < LPAD; jj++) mx = fmaxf(mx, vj[jj]);
  float sum = 0.f;
  #pragma unroll
  for (int jj = 0; jj < LPAD; jj++) sum += expf(vj[jj] - mx);
  if (i == 0) out_ll[b] = gold[b] - (mx + logf(sum));
}

// ================================================================ launch
extern "C" void kernel_launch(void* const* d_in, const int* in_sizes, int n_in,
                              void* d_out, int out_size, void* d_ws, size_t ws_size,
                              hipStream_t stream)
{
  (void)in_sizes; (void)n_in; (void)out_size; (void)ws_size;
  const int*   token_ids = (const int*)d_in[0];
  const int*   char_ids  = (const int*)d_in[1];
  const int*   lens      = (const int*)d_in[2];
  const int*   labels    = (const int*)d_in[3];
  const float* word_embed= (const float*)d_in[4];
  const float* char_embed= (const float*)d_in[5];
  const float* w2 = (const float*)d_in[6];  const float* cb2 = (const float*)d_in[7];
  const float* w3 = (const float*)d_in[8];  const float* cb3 = (const float*)d_in[9];
  const float* w4 = (const float*)d_in[10]; const float* cb4 = (const float*)d_in[11];
  const float* w5 = (const float*)d_in[12]; const float* cb5 = (const float*)d_in[13];
  const float* ff_w = (const float*)d_in[14]; const float* ff_b = (const float*)d_in[15];
  const float* wgate_w = (const float*)d_in[16];
  const float* cgate_w = (const float*)d_in[17];
  const float* gate_w  = (const float*)d_in[18];
  const float* wih_f = (const float*)d_in[19]; const float* whh_f = (const float*)d_in[20];
  const float* b_f   = (const float*)d_in[21];
  const float* wih_b = (const float*)d_in[22]; const float* whh_b = (const float*)d_in[23];
  const float* b_b   = (const float*)d_in[24];
  const float* out_w = (const float*)d_in[25]; const float* out_b = (const float*)d_in[26];
  const float* trn   = (const float*)d_in[27];

  char* ws = (char*)d_ws;
  size_t off = 0;
  auto alloc = [&](size_t bytes) { void* p = ws + off; off += (bytes + 255) & ~(size_t)255; return p; };
  float* ch       = (float*)alloc((size_t)NWORD * 256 * 4);
  float* word_in  = (float*)alloc((size_t)NWORD * WDIM * 4);
  float* char_in  = (float*)alloc((size_t)NWORD * WDIM * 4);
  float* t1       = (float*)alloc((size_t)NWORD * WDIM * 4);
  float* gbuf     = (float*)alloc((size_t)NWORD * WDIM * 4);
  float* feats    = (float*)alloc((size_t)NWORD * WDIM * 4);
  unsigned short* xgf = (unsigned short*)alloc((size_t)NWORD * 2048 * 2);
  unsigned short* xgb = (unsigned short*)alloc((size_t)NWORD * 2048 * 2);
  float* lstm_o   = (float*)alloc((size_t)NWORD * 1024 * 4);
  unsigned short* hglob = (unsigned short*)alloc((size_t)2 * 2 * NB * HD * 2);
  float* gold     = (float*)alloc((size_t)NB * 4);
  unsigned* flags = (unsigned*)alloc(256);

  float* outp   = (float*)d_out;
  float* loglik = outp;
  float* logits = outp + NB;

  conv_kernel<<<NWORD, 256, 0, stream>>>(char_ids, char_embed, w2, cb2, w3, cb3, w4, cb4, w5, cb5, ch);
  gather_word_kernel<<<(NWORD * WDIM + 255) / 256, 256, 0, stream>>>(token_ids, word_embed, word_in);
  gemm_bt_kernel<<<32 * 3, 256, 0, stream>>>(ch, ff_w, ff_b, nullptr, char_in, nullptr, NWORD, 300, 256, 0, 3);
  gemm_bt_kernel<<<32 * 3, 256, 0, stream>>>(word_in, wgate_w, nullptr, nullptr, t1, nullptr, NWORD, 300, 300, 0, 3);
  gemm_bt_kernel<<<32 * 3, 256, 0, stream>>>(char_in, cgate_w, nullptr, t1, t1, nullptr, NWORD, 300, 300, 1, 3);
  gemm_bt_kernel<<<32 * 3, 256, 0, stream>>>(t1, gate_w, nullptr, nullptr, gbuf, nullptr, NWORD, 300, 300, 2, 3);
  feats_kernel<<<(NWORD * WDIM + 255) / 256, 256, 0, stream>>>(gbuf, word_in, char_in, feats, flags);
  gemm_bt_kernel<<<32 * 16, 256, 0, stream>>>(feats, wih_f, b_f, nullptr, nullptr, xgf, NWORD, 2048, 300, 0, 16);
  gemm_bt_kernel<<<32 * 16, 256, 0, stream>>>(feats, wih_b, b_b, nullptr, nullptr, xgb, NWORD, 2048, 300, 0, 16);
  {
    void* args[] = { (void*)&xgf, (void*)&xgb, (void*)&whh_f, (void*)&whh_b,
                     (void*)&lens, (void*)&lstm_o, (void*)&hglob, (void*)&flags };
    hipLaunchCooperativeKernel((void*)lstm_kernel, dim3(LSTM_BLOCKS), dim3(512), args, 0, stream);
  }
  logits_kernel<<<NWORD, 64, 0, stream>>>(lstm_o, out_w, out_b, logits);
  crf_gold_kernel<<<NB, 64, 0, stream>>>(logits, labels, lens, trn, gold);
  crf_norm_kernel<<<NB, 64, 0, stream>>>(logits, lens, trn, gold, loglik);
}